// Round 1
// baseline (1568.318 us; speedup 1.0000x reference)
//
#include <hip/hip_runtime.h>

typedef __attribute__((ext_vector_type(8))) short bf16x8;
typedef __attribute__((ext_vector_type(4))) float f32x4;

__device__ __forceinline__ unsigned short f2bf(float x) {
    union { float f; unsigned u; } c; c.f = x;
    unsigned u = c.u + 0x7fffu + ((c.u >> 16) & 1u);
    return (unsigned short)(u >> 16);
}
__device__ __forceinline__ unsigned pack2(float a, float b) {
    return (unsigned)f2bf(a) | ((unsigned)f2bf(b) << 16);
}
__device__ __forceinline__ float sigm(float x) { return 1.f / (1.f + __expf(-x)); }
__device__ __forceinline__ float tanh_(float x) { return 1.f - 2.f / (__expf(2.f * x) + 1.f); }

// ---------------------------------------------------------------------------
// prep: table[v][c] = emb[v] . w_ih[srow(c)] + b_ih + b_hh   (c = permuted col)
//       Wp[c][k]  = bf16(w_hh[srow(c)][k])
//       w1p       = bf16(w1)  (no permutation)
//       imgb[b][h]= bf16(img_rep[b] . proc_w[h] + proc_b[h])
// Permutation: col c (global) -> tile t=c>>7, c7=c&127 with bits
//   unit U = t*32 + ((c7>>6)&1)*16 + (c7&15), gate g = (c7>>4)&3, srow = g*512+U
// ---------------------------------------------------------------------------
__global__ __launch_bounds__(256) void prep_k(
    const float* __restrict__ emb, const float* __restrict__ w_ih,
    const float* __restrict__ b_ih, const float* __restrict__ b_hh,
    const float* __restrict__ w_hh, const float* __restrict__ w1,
    const float* __restrict__ imgr, const float* __restrict__ procw,
    const float* __restrict__ procb,
    float* __restrict__ table, unsigned short* __restrict__ Wp,
    unsigned short* __restrict__ w1p, unsigned short* __restrict__ imgb)
{
    int wg = blockIdx.x, tid = threadIdx.x;
    if (wg < 256) {
        int id = wg * 256 + tid;              // [0, 65536): v*2048 + c
        int v = id >> 11, c = id & 2047;
        int c7 = c & 127, tt = c >> 7;
        int srow = ((c7 >> 4) & 3) * 512 + tt * 32 + ((c7 >> 6) & 1) * 16 + (c7 & 15);
        const float4* e4 = (const float4*)(emb + v * 256);
        const float4* w4 = (const float4*)(w_ih + srow * 256);
        float a = 0.f;
        #pragma unroll 8
        for (int k = 0; k < 64; ++k) {
            float4 x = e4[k], y = w4[k];
            a += x.x * y.x + x.y * y.y + x.z * y.z + x.w * y.w;
        }
        table[id] = a + b_ih[srow] + b_hh[srow];
    } else if (wg < 768) {
        int id = (wg - 256) * 256 + tid;      // [0, 131072): c*64 + j  (8 elems each)
        int c = id >> 6, j = id & 63;
        int c7 = c & 127, tt = c >> 7;
        int srow = ((c7 >> 4) & 3) * 512 + tt * 32 + ((c7 >> 6) & 1) * 16 + (c7 & 15);
        const float4* s4 = (const float4*)(w_hh + srow * 512 + j * 8);
        float4 x = s4[0], y = s4[1];
        uint4 r;
        r.x = pack2(x.x, x.y); r.y = pack2(x.z, x.w);
        r.z = pack2(y.x, y.y); r.w = pack2(y.z, y.w);
        *(uint4*)(Wp + c * 512 + j * 8) = r;
    } else if (wg < 1024) {
        int id = (wg - 768) * 256 + tid;      // [0, 65536): 8 elems each of w1
        const float4* s4 = (const float4*)(w1 + id * 8);
        float4 x = s4[0], y = s4[1];
        uint4 r;
        r.x = pack2(x.x, x.y); r.y = pack2(x.z, x.w);
        r.z = pack2(y.x, y.y); r.w = pack2(y.z, y.w);
        *(uint4*)(w1p + id * 8) = r;
    } else {
        int id = (wg - 1024) * 256 + tid;     // [0, 524288): b*512 + h
        int b = id >> 9, h = id & 511;
        const float* ir = imgr + b * 13;
        const float* pw = procw + h * 13;
        float a = procb[h];
        #pragma unroll
        for (int k = 0; k < 13; ++k) a += ir[k] * pw[k];
        imgb[id] = f2bf(a);
    }
}

// ---------------------------------------------------------------------------
// step 1 (h_prev = 0): gates = table row only
// ---------------------------------------------------------------------------
__global__ __launch_bounds__(256) void init_k(
    const float* __restrict__ table, const int* __restrict__ msgs,
    unsigned short* __restrict__ h1, float* __restrict__ c1)
{
    int id = blockIdx.x * 256 + threadIdx.x;  // [0, 524288): b*512 + U
    int b = id >> 9, U = id & 511;
    int v = msgs[b * 64];
    int tt = U >> 5, b6 = (U >> 4) & 1, low = U & 15;
    const float* tr = table + v * 2048 + tt * 128 + b6 * 64 + low;
    float gi = tr[0], gg = tr[32], go = tr[48];
    float cn = sigm(gi) * tanh_(gg);
    float hn = sigm(go) * tanh_(cn);
    c1[id] = cn;
    h1[id] = f2bf(hn);
}

// ---------------------------------------------------------------------------
// LSTM step: gates[1024,2048] = h_prev(bf16) @ Wp^T + table[msg] ; fused cell.
// Grid (16 n-tiles, 16 m-tiles), 256 thr = 4 waves (2 M x 2 N), wave 32x64.
// LDS A[64][64] / B[128][64] bf16, 16B-slot XOR swizzle by (row&7).
// Within a 128-col tile: c7 = wc*64 + gate*16 + lane15 -> gate == col-frag idx.
// ---------------------------------------------------------------------------
__global__ __launch_bounds__(256) void step_k(
    const unsigned short* __restrict__ hprev, unsigned short* __restrict__ hcur,
    float* __restrict__ cst, const float* __restrict__ table,
    const unsigned short* __restrict__ Wp, const int* __restrict__ msgs, int s)
{
    __shared__ uint4 ldsA[512];    // [64 rows][8 slots of 16B]
    __shared__ uint4 ldsB[1024];   // [128 cols][8 slots]
    __shared__ float ldsT[4096];   // table tile [32 v][128 c]
    const int tid = threadIdx.x;
    const int lane = tid & 63, wid = tid >> 6;
    const int wr = wid >> 1, wc = wid & 1;
    const int l15 = lane & 15, l4 = lane >> 4;
    const int mbase = blockIdx.y * 64;
    const int t = blockIdx.x;

    {   // stage table tile (16 KB)
        const uint4* tg = (const uint4*)table;     // row = 512 uint4
        uint4* tl = (uint4*)ldsT;
        #pragma unroll
        for (int j = 0; j < 4; ++j) {
            int p = tid + j * 256;                 // [0,1024)
            tl[p] = tg[(p >> 5) * 512 + t * 32 + (p & 31)];
        }
    }

    const uint4* hg = (const uint4*)hprev;   // h row = 64 uint4
    const uint4* wg4 = (const uint4*)Wp;     // Wp row = 64 uint4

    f32x4 acc[2][4] = {};
    uint4 ra[2], rb[4];

    // chunk 0
    #pragma unroll
    for (int j = 0; j < 2; ++j) {
        int p = tid + j * 256, row = p >> 3, ss = (p & 7) ^ (row & 7);
        ra[j] = hg[(mbase + row) * 64 + ss];
    }
    #pragma unroll
    for (int j = 0; j < 4; ++j) {
        int p = tid + j * 256, col = p >> 3, ss = (p & 7) ^ (col & 7);
        rb[j] = wg4[(t * 128 + col) * 64 + ss];
    }
    #pragma unroll
    for (int j = 0; j < 2; ++j) ldsA[tid + j * 256] = ra[j];
    #pragma unroll
    for (int j = 0; j < 4; ++j) ldsB[tid + j * 256] = rb[j];
    __syncthreads();

    for (int kc = 0; kc < 8; ++kc) {
        if (kc < 7) {   // prefetch next chunk into regs (overlaps MFMA)
            #pragma unroll
            for (int j = 0; j < 2; ++j) {
                int p = tid + j * 256, row = p >> 3, ss = (p & 7) ^ (row & 7);
                ra[j] = hg[(mbase + row) * 64 + (kc + 1) * 8 + ss];
            }
            #pragma unroll
            for (int j = 0; j < 4; ++j) {
                int p = tid + j * 256, col = p >> 3, ss = (p & 7) ^ (col & 7);
                rb[j] = wg4[(t * 128 + col) * 64 + (kc + 1) * 8 + ss];
            }
        }
        #pragma unroll
        for (int kg = 0; kg < 2; ++kg) {
            bf16x8 af[2], bfr[4];
            #pragma unroll
            for (int rf = 0; rf < 2; ++rf) {
                int row = wr * 32 + rf * 16 + l15;
                int sst = (kg * 4 + l4) ^ (row & 7);
                af[rf] = *(const bf16x8*)&ldsA[row * 8 + sst];
            }
            #pragma unroll
            for (int cf = 0; cf < 4; ++cf) {
                int col = wc * 64 + cf * 16 + l15;
                int sst = (kg * 4 + l4) ^ (col & 7);
                bfr[cf] = *(const bf16x8*)&ldsB[col * 8 + sst];
            }
            #pragma unroll
            for (int rf = 0; rf < 2; ++rf)
                #pragma unroll
                for (int cf = 0; cf < 4; ++cf)
                    acc[rf][cf] = __builtin_amdgcn_mfma_f32_16x16x32_bf16(
                        af[rf], bfr[cf], acc[rf][cf], 0, 0, 0);
        }
        if (kc < 7) {
            __syncthreads();
            #pragma unroll
            for (int j = 0; j < 2; ++j) ldsA[tid + j * 256] = ra[j];
            #pragma unroll
            for (int j = 0; j < 4; ++j) ldsB[tid + j * 256] = rb[j];
            __syncthreads();
        }
    }

    // fused LSTM cell: acc[rf][gate][reg] ; C/D layout col=lane&15, row=l4*4+reg
    #pragma unroll
    for (int rf = 0; rf < 2; ++rf) {
        #pragma unroll
        for (int reg = 0; reg < 4; ++reg) {
            int b = mbase + wr * 32 + rf * 16 + l4 * 4 + reg;
            int v = msgs[b * 64 + s];
            const float* tr = ldsT + v * 128 + wc * 64 + l15;
            float gi = acc[rf][0][reg] + tr[0];
            float gf = acc[rf][1][reg] + tr[16];
            float gg = acc[rf][2][reg] + tr[32];
            float go = acc[rf][3][reg] + tr[48];
            int U = t * 32 + wc * 16 + l15;
            int idx = b * 512 + U;
            float cp = cst[idx];
            float cn = sigm(gf) * cp + sigm(gi) * tanh_(gg);
            float hn = sigm(go) * tanh_(cn);
            cst[idx] = cn;
            hcur[idx] = f2bf(hn);
        }
    }
}

// ---------------------------------------------------------------------------
// hidden = relu([h64, img] @ w1^T + b1) : M=1024, N=512, K=1024 (bf16 MFMA)
// A cols 0..511 from h64(bf16), 512..1023 from imgb(bf16). Grid (4,16).
// ---------------------------------------------------------------------------
__global__ __launch_bounds__(256) void mlp_k(
    const unsigned short* __restrict__ hfin, const unsigned short* __restrict__ imgb,
    const unsigned short* __restrict__ w1p, const float* __restrict__ b1,
    float* __restrict__ hid)
{
    __shared__ uint4 ldsA[512];
    __shared__ uint4 ldsB[1024];
    const int tid = threadIdx.x;
    const int lane = tid & 63, wid = tid >> 6;
    const int wr = wid >> 1, wc = wid & 1;
    const int l15 = lane & 15, l4 = lane >> 4;
    const int mbase = blockIdx.y * 64;
    const int t = blockIdx.x;    // [0,4)

    const uint4* ha = (const uint4*)hfin;
    const uint4* ia = (const uint4*)imgb;
    const uint4* wb = (const uint4*)w1p;    // row = 128 uint4 (K=1024)

    f32x4 acc[2][4] = {};
    uint4 ra[2], rb[4];

    #pragma unroll
    for (int j = 0; j < 2; ++j) {
        int p = tid + j * 256, row = p >> 3, ss = (p & 7) ^ (row & 7);
        ra[j] = ha[(mbase + row) * 64 + ss];
    }
    #pragma unroll
    for (int j = 0; j < 4; ++j) {
        int p = tid + j * 256, col = p >> 3, ss = (p & 7) ^ (col & 7);
        rb[j] = wb[(t * 128 + col) * 128 + ss];
    }
    #pragma unroll
    for (int j = 0; j < 2; ++j) ldsA[tid + j * 256] = ra[j];
    #pragma unroll
    for (int j = 0; j < 4; ++j) ldsB[tid + j * 256] = rb[j];
    __syncthreads();

    for (int kc = 0; kc < 16; ++kc) {
        if (kc < 15) {
            int kn = kc + 1;
            #pragma unroll
            for (int j = 0; j < 2; ++j) {
                int p = tid + j * 256, row = p >> 3, ss = (p & 7) ^ (row & 7);
                ra[j] = (kn < 8) ? ha[(mbase + row) * 64 + kn * 8 + ss]
                                 : ia[(mbase + row) * 64 + (kn - 8) * 8 + ss];
            }
            #pragma unroll
            for (int j = 0; j < 4; ++j) {
                int p = tid + j * 256, col = p >> 3, ss = (p & 7) ^ (col & 7);
                rb[j] = wb[(t * 128 + col) * 128 + kn * 8 + ss];
            }
        }
        #pragma unroll
        for (int kg = 0; kg < 2; ++kg) {
            bf16x8 af[2], bfr[4];
            #pragma unroll
            for (int rf = 0; rf < 2; ++rf) {
                int row = wr * 32 + rf * 16 + l15;
                int sst = (kg * 4 + l4) ^ (row & 7);
                af[rf] = *(const bf16x8*)&ldsA[row * 8 + sst];
            }
            #pragma unroll
            for (int cf = 0; cf < 4; ++cf) {
                int col = wc * 64 + cf * 16 + l15;
                int sst = (kg * 4 + l4) ^ (col & 7);
                bfr[cf] = *(const bf16x8*)&ldsB[col * 8 + sst];
            }
            #pragma unroll
            for (int rf = 0; rf < 2; ++rf)
                #pragma unroll
                for (int cf = 0; cf < 4; ++cf)
                    acc[rf][cf] = __builtin_amdgcn_mfma_f32_16x16x32_bf16(
                        af[rf], bfr[cf], acc[rf][cf], 0, 0, 0);
        }
        if (kc < 15) {
            __syncthreads();
            #pragma unroll
            for (int j = 0; j < 2; ++j) ldsA[tid + j * 256] = ra[j];
            #pragma unroll
            for (int j = 0; j < 4; ++j) ldsB[tid + j * 256] = rb[j];
            __syncthreads();
        }
    }

    #pragma unroll
    for (int rf = 0; rf < 2; ++rf) {
        #pragma unroll
        for (int reg = 0; reg < 4; ++reg) {
            int b = mbase + wr * 32 + rf * 16 + l4 * 4 + reg;
            #pragma unroll
            for (int cf = 0; cf < 4; ++cf) {
                int n = t * 128 + wc * 64 + cf * 16 + l15;
                float o = acc[rf][cf][reg] + b1[n];
                hid[b * 512 + n] = fmaxf(o, 0.f);
            }
        }
    }
}

// prediction[b][j] = hidden[b] . w2[j] + b2[j]
__global__ __launch_bounds__(256) void pred_k(
    const float* __restrict__ hid, const float* __restrict__ w2,
    const float* __restrict__ b2, float* __restrict__ out)
{
    int id = blockIdx.x * 256 + threadIdx.x;
    if (id >= 2048) return;
    int b = id >> 1, j = id & 1;
    const float4* hr = (const float4*)(hid + b * 512);
    const float4* wr = (const float4*)(w2 + j * 512);
    float a = 0.f;
    #pragma unroll 8
    for (int k = 0; k < 128; ++k) {
        float4 x = hr[k], y = wr[k];
        a += x.x * y.x + x.y * y.y + x.z * y.z + x.w * y.w;
    }
    out[id] = a + b2[j];
}

// emb output gather: out[b][s][:] = embedding[msg[b][s]][:]
__global__ __launch_bounds__(256) void gather_k(
    const float* __restrict__ emb, const int* __restrict__ msgs,
    float* __restrict__ out)
{
    const float4* e4 = (const float4*)emb;
    float4* o4 = (float4*)out;
    int id = blockIdx.x * 256 + threadIdx.x;
    #pragma unroll
    for (int it = 0; it < 4; ++it) {
        int p = id + it * 1048576;           // [0, 4194304)
        int bs = p >> 6, e = p & 63;
        int v = msgs[bs];
        o4[p] = e4[v * 64 + e];
    }
}

extern "C" void kernel_launch(void* const* d_in, const int* in_sizes, int n_in,
                              void* d_out, int out_size, void* d_ws, size_t ws_size,
                              hipStream_t stream)
{
    const float* imgr  = (const float*)d_in[0];
    const int*   msgs  = (const int*)d_in[1];
    const float* emb   = (const float*)d_in[2];
    const float* w_ih  = (const float*)d_in[3];
    const float* w_hh  = (const float*)d_in[4];
    const float* b_ih  = (const float*)d_in[5];
    const float* b_hh  = (const float*)d_in[6];
    const float* procw = (const float*)d_in[7];
    const float* procb = (const float*)d_in[8];
    const float* w1    = (const float*)d_in[9];
    const float* b1    = (const float*)d_in[10];
    const float* w2    = (const float*)d_in[11];
    const float* b2    = (const float*)d_in[12];
    float* outp = (float*)d_out;

    const size_t NEED = (size_t)(256 << 10) + (10u << 20);
    // Fallback scratch: the emb output region (67 MB) is written LAST by
    // gather_k, so it is safely usable as scratch by every earlier kernel.
    char* ws = (ws_size >= NEED) ? (char*)d_ws : (char*)(outp + 2048);

    float*          table = (float*)(ws);                                  // 256 KB
    unsigned short* Wp    = (unsigned short*)(ws + (256 << 10));           // 2 MB
    unsigned short* h0    = (unsigned short*)(ws + (256 << 10) + (2u << 20)); // 1 MB
    unsigned short* h1b   = (unsigned short*)(ws + (256 << 10) + (3u << 20)); // 1 MB
    float*          cst   = (float*)(ws + (256 << 10) + (4u << 20));       // 2 MB
    unsigned short* imgb  = (unsigned short*)(ws + (256 << 10) + (6u << 20)); // 1 MB
    unsigned short* w1p   = (unsigned short*)(ws + (256 << 10) + (7u << 20)); // 1 MB
    float*          hid   = (float*)(ws + (256 << 10) + (8u << 20));       // 2 MB

    prep_k<<<3072, 256, 0, stream>>>(emb, w_ih, b_ih, b_hh, w_hh, w1, imgr,
                                     procw, procb, table, Wp, w1p, imgb);
    init_k<<<2048, 256, 0, stream>>>(table, msgs, h0, cst);

    unsigned short* bufs[2] = { h0, h1b };
    for (int t = 2; t <= 64; ++t) {
        step_k<<<dim3(16, 16), 256, 0, stream>>>(
            bufs[(t - 2) & 1], bufs[(t - 1) & 1], cst, table, Wp, msgs, t - 1);
    }
    // h64 ends in bufs[(64-1)&1] = h1b
    mlp_k<<<dim3(4, 16), 256, 0, stream>>>(h1b, imgb, w1p, b1, hid);
    pred_k<<<8, 256, 0, stream>>>(hid, w2, b2, outp);
    gather_k<<<4096, 256, 0, stream>>>(emb, msgs, outp + 2048);
}

// Round 2
// 1309.435 us; speedup vs baseline: 1.1977x; 1.1977x over previous
//
#include <hip/hip_runtime.h>

typedef __attribute__((ext_vector_type(8))) short bf16x8;
typedef __attribute__((ext_vector_type(4))) float f32x4;

__device__ __forceinline__ unsigned short f2bf(float x) {
    union { float f; unsigned u; } c; c.f = x;
    unsigned u = c.u + 0x7fffu + ((c.u >> 16) & 1u);
    return (unsigned short)(u >> 16);
}
__device__ __forceinline__ unsigned pack2(float a, float b) {
    return (unsigned)f2bf(a) | ((unsigned)f2bf(b) << 16);
}
__device__ __forceinline__ float sigm(float x) { return 1.f / (1.f + __expf(-x)); }
__device__ __forceinline__ float tanh_(float x) { return 1.f - 2.f / (__expf(2.f * x) + 1.f); }

// ---------------------------------------------------------------------------
// prep: table[v][c] = emb[v] . w_ih[srow(c)] + b_ih + b_hh   (c = permuted col)
//       Wp[c][k]  = bf16(w_hh[srow(c)][k]);  w1p = bf16(w1)
//       imgb[b][h]= bf16(img_rep[b] . proc_w[h] + proc_b[h])
// Permutation: c -> tile t=c>>7, c7=c&127:
//   unit U = t*32 + ((c7>>6)&1)*16 + (c7&15), gate g = (c7>>4)&3, srow = g*512+U
// ---------------------------------------------------------------------------
__global__ __launch_bounds__(256) void prep_k(
    const float* __restrict__ emb, const float* __restrict__ w_ih,
    const float* __restrict__ b_ih, const float* __restrict__ b_hh,
    const float* __restrict__ w_hh, const float* __restrict__ w1,
    const float* __restrict__ imgr, const float* __restrict__ procw,
    const float* __restrict__ procb,
    float* __restrict__ table, unsigned short* __restrict__ Wp,
    unsigned short* __restrict__ w1p, unsigned short* __restrict__ imgb)
{
    int wg = blockIdx.x, tid = threadIdx.x;
    if (wg < 256) {
        int id = wg * 256 + tid;              // v*2048 + c
        int v = id >> 11, c = id & 2047;
        int c7 = c & 127, tt = c >> 7;
        int srow = ((c7 >> 4) & 3) * 512 + tt * 32 + ((c7 >> 6) & 1) * 16 + (c7 & 15);
        const float4* e4 = (const float4*)(emb + v * 256);
        const float4* w4 = (const float4*)(w_ih + srow * 256);
        float a = 0.f;
        #pragma unroll 8
        for (int k = 0; k < 64; ++k) {
            float4 x = e4[k], y = w4[k];
            a += x.x * y.x + x.y * y.y + x.z * y.z + x.w * y.w;
        }
        table[id] = a + b_ih[srow] + b_hh[srow];
    } else if (wg < 768) {
        int id = (wg - 256) * 256 + tid;      // c*64 + j  (8 elems each)
        int c = id >> 6, j = id & 63;
        int c7 = c & 127, tt = c >> 7;
        int srow = ((c7 >> 4) & 3) * 512 + tt * 32 + ((c7 >> 6) & 1) * 16 + (c7 & 15);
        const float4* s4 = (const float4*)(w_hh + srow * 512 + j * 8);
        float4 x = s4[0], y = s4[1];
        uint4 r;
        r.x = pack2(x.x, x.y); r.y = pack2(x.z, x.w);
        r.z = pack2(y.x, y.y); r.w = pack2(y.z, y.w);
        *(uint4*)(Wp + c * 512 + j * 8) = r;
    } else if (wg < 1024) {
        int id = (wg - 768) * 256 + tid;      // 8 elems each of w1
        const float4* s4 = (const float4*)(w1 + id * 8);
        float4 x = s4[0], y = s4[1];
        uint4 r;
        r.x = pack2(x.x, x.y); r.y = pack2(x.z, x.w);
        r.z = pack2(y.x, y.y); r.w = pack2(y.z, y.w);
        *(uint4*)(w1p + id * 8) = r;
    } else {
        int id = (wg - 1024) * 256 + tid;     // b*512 + h
        int b = id >> 9, h = id & 511;
        const float* ir = imgr + b * 13;
        const float* pw = procw + h * 13;
        float a = procb[h];
        #pragma unroll
        for (int k = 0; k < 13; ++k) a += ir[k] * pw[k];
        imgb[id] = f2bf(a);
    }
}

// ---------------------------------------------------------------------------
// Persistent LSTM: 256 WGs x 512 thr, 1 WG/CU (LDS 148 KB). WG x: group
// g=(x&7)|(((x>>7)&1)<<3) (rows g*64..+64), tile t=(x>>3)&15 (units t*32..+32).
// W slice + table tile + msgs stationary in LDS; cell state in registers;
// h double-buffered in global; per-group monotonic flag sync per step.
// ---------------------------------------------------------------------------
__global__ __launch_bounds__(512, 2) void lstm_k(
    const float* __restrict__ table, const unsigned short* __restrict__ Wp,
    const int* __restrict__ msgs, unsigned short* __restrict__ h0,
    unsigned short* __restrict__ h1, unsigned* __restrict__ flags)
{
    extern __shared__ char smem[];
    uint4* Bsh = (uint4*)smem;                                     // [128][64] swz
    float* Tsh = (float*)(smem + 131072);                          // [32 v][128 c7]
    unsigned char* Msh = (unsigned char*)(smem + 131072 + 16384);  // [64 s][64 row]

    const int tid = threadIdx.x;
    const int lane = tid & 63, wid = tid >> 6;
    const int wr = wid >> 1, wc = wid & 1;
    const int l15 = lane & 15, l4 = lane >> 4;
    const int x = blockIdx.x;
    const int g = (x & 7) | (((x >> 7) & 1) << 3);
    const int t = (x >> 3) & 15;

    const uint4* wg4 = (const uint4*)Wp;
    #pragma unroll
    for (int it = 0; it < 16; ++it) {
        int p = tid + it * 512;
        int col = p >> 6, s_ = p & 63;
        Bsh[col * 64 + (s_ ^ (col & 7))] = wg4[(t * 128 + col) * 64 + s_];
    }
    const uint4* tg = (const uint4*)table;
    uint4* T4 = (uint4*)Tsh;
    #pragma unroll
    for (int it = 0; it < 2; ++it) {
        int p = tid + it * 512;
        T4[p] = tg[(p >> 5) * 512 + t * 32 + (p & 31)];
    }
    #pragma unroll
    for (int it = 0; it < 8; ++it) {
        int p = tid + it * 512;
        int row = p >> 6, s_ = p & 63;
        Msh[s_ * 64 + row] = (unsigned char)msgs[(g * 64 + row) * 64 + s_];
    }
    __syncthreads();

    float creg[4] = {0.f, 0.f, 0.f, 0.f};
    const int arow = g * 64 + wr * 16 + l15;   // A-fragment row (global)
    const int brow_base = wr * 16 + l4 * 4;    // cell-update local row base
    const int Ucol = t * 32 + wc * 16 + l15;   // owned h unit
    const int swz = l15 & 7;

    for (int s = 0; s < 64; ++s) {
        f32x4 acc[4] = {};
        if (s > 0) {
            if (tid == 0) {
                unsigned tgt = (unsigned)(16 * s);
                while (__hip_atomic_load(&flags[g], __ATOMIC_ACQUIRE,
                                         __HIP_MEMORY_SCOPE_AGENT) < tgt)
                    __builtin_amdgcn_s_sleep(1);
            }
            __syncthreads();
            const uint4* hp = (const uint4*)((s & 1) ? h0 : h1);
            bf16x8 A[16];
            #pragma unroll
            for (int kg = 0; kg < 16; ++kg)
                A[kg] = *(const bf16x8*)&hp[arow * 64 + kg * 4 + l4];
            #pragma unroll
            for (int kg = 0; kg < 16; ++kg) {
                bf16x8 bfr[4];
                #pragma unroll
                for (int cf = 0; cf < 4; ++cf) {
                    int c7 = wc * 64 + cf * 16 + l15;
                    bfr[cf] = *(const bf16x8*)&Bsh[c7 * 64 + ((kg * 4 + l4) ^ swz)];
                }
                #pragma unroll
                for (int cf = 0; cf < 4; ++cf)
                    acc[cf] = __builtin_amdgcn_mfma_f32_16x16x32_bf16(
                        A[kg], bfr[cf], acc[cf], 0, 0, 0);
            }
        }
        unsigned short* hw = (s & 1) ? h1 : h0;
        #pragma unroll
        for (int reg = 0; reg < 4; ++reg) {
            int bl = brow_base + reg;
            int v = Msh[s * 64 + bl];
            const float* tr = Tsh + v * 128 + wc * 64 + l15;
            float gi = acc[0][reg] + tr[0];
            float gf = acc[1][reg] + tr[16];
            float gg = acc[2][reg] + tr[32];
            float go = acc[3][reg] + tr[48];
            float cn = sigm(gf) * creg[reg] + sigm(gi) * tanh_(gg);
            creg[reg] = cn;
            hw[(g * 64 + bl) * 512 + Ucol] = f2bf(sigm(go) * tanh_(cn));
        }
        __syncthreads();   // all stores complete (vmcnt drained at barrier)
        if (tid == 0) {
            __threadfence();   // agent release: flush to coherent point
            __hip_atomic_fetch_add(&flags[g], 1u, __ATOMIC_RELEASE,
                                   __HIP_MEMORY_SCOPE_AGENT);
        }
    }
}

// ---------------------------------------------------------------------------
// hidden = relu([h64, img] @ w1^T + b1): M=1024,N=512,K=1024. Grid (16,16),
// tile 64x32, 4 waves split M, wave 16x32, acc[1][2].
// ---------------------------------------------------------------------------
__global__ __launch_bounds__(256) void mlp2_k(
    const unsigned short* __restrict__ hfin, const unsigned short* __restrict__ imgb,
    const unsigned short* __restrict__ w1p, const float* __restrict__ b1,
    float* __restrict__ hid)
{
    __shared__ uint4 ldsA[512];   // [64 rows][8 slots]
    __shared__ uint4 ldsB[256];   // [32 cols][8 slots]
    const int tid = threadIdx.x;
    const int lane = tid & 63, wid = tid >> 6;
    const int l15 = lane & 15, l4 = lane >> 4;
    const int mbase = blockIdx.y * 64;
    const int t = blockIdx.x;     // [0,16)

    const uint4* ha = (const uint4*)hfin;
    const uint4* ia = (const uint4*)imgb;
    const uint4* wb = (const uint4*)w1p;   // rows of 128 uint4

    f32x4 acc[2] = {};
    uint4 ra[2], rb1;

    #pragma unroll
    for (int j = 0; j < 2; ++j) {
        int p = tid + j * 256, row = p >> 3, ss = (p & 7) ^ (row & 7);
        ra[j] = ha[(mbase + row) * 64 + ss];
    }
    {
        int col = tid >> 3, ss = (tid & 7) ^ (col & 7);
        rb1 = wb[(t * 32 + col) * 128 + ss];
    }
    #pragma unroll
    for (int j = 0; j < 2; ++j) ldsA[tid + j * 256] = ra[j];
    ldsB[tid] = rb1;
    __syncthreads();

    for (int kc = 0; kc < 16; ++kc) {
        if (kc < 15) {
            int kn = kc + 1;
            #pragma unroll
            for (int j = 0; j < 2; ++j) {
                int p = tid + j * 256, row = p >> 3, ss = (p & 7) ^ (row & 7);
                ra[j] = (kn < 8) ? ha[(mbase + row) * 64 + kn * 8 + ss]
                                 : ia[(mbase + row) * 64 + (kn - 8) * 8 + ss];
            }
            int col = tid >> 3, ss = (tid & 7) ^ (col & 7);
            rb1 = wb[(t * 32 + col) * 128 + kn * 8 + ss];
        }
        #pragma unroll
        for (int kg = 0; kg < 2; ++kg) {
            int row = wid * 16 + l15;
            bf16x8 af = *(const bf16x8*)&ldsA[row * 8 + ((kg * 4 + l4) ^ (row & 7))];
            #pragma unroll
            for (int cf = 0; cf < 2; ++cf) {
                int col = cf * 16 + l15;
                bf16x8 bf = *(const bf16x8*)&ldsB[col * 8 + ((kg * 4 + l4) ^ (col & 7))];
                acc[cf] = __builtin_amdgcn_mfma_f32_16x16x32_bf16(af, bf, acc[cf], 0, 0, 0);
            }
        }
        if (kc < 15) {
            __syncthreads();
            #pragma unroll
            for (int j = 0; j < 2; ++j) ldsA[tid + j * 256] = ra[j];
            ldsB[tid] = rb1;
            __syncthreads();
        }
    }

    #pragma unroll
    for (int reg = 0; reg < 4; ++reg) {
        int b = mbase + wid * 16 + l4 * 4 + reg;
        #pragma unroll
        for (int cf = 0; cf < 2; ++cf) {
            int n = t * 32 + cf * 16 + l15;
            hid[b * 512 + n] = fmaxf(acc[cf][reg] + b1[n], 0.f);
        }
    }
}

// prediction: one wave per batch row, shuffle-reduce over 512 f32.
__global__ __launch_bounds__(256) void pred2_k(
    const float* __restrict__ hid, const float* __restrict__ w2,
    const float* __restrict__ b2, float* __restrict__ out)
{
    int wid = threadIdx.x >> 6, lane = threadIdx.x & 63;
    int b = blockIdx.x * 4 + wid;
    const float4* hr = (const float4*)(hid + b * 512);
    const float4* wA = (const float4*)(w2);
    const float4* wB = (const float4*)(w2 + 512);
    float a0 = 0.f, a1 = 0.f;
    #pragma unroll
    for (int j = 0; j < 2; ++j) {
        float4 h4 = hr[lane * 2 + j];
        float4 x0 = wA[lane * 2 + j], x1 = wB[lane * 2 + j];
        a0 += h4.x * x0.x + h4.y * x0.y + h4.z * x0.z + h4.w * x0.w;
        a1 += h4.x * x1.x + h4.y * x1.y + h4.z * x1.z + h4.w * x1.w;
    }
    #pragma unroll
    for (int off = 32; off > 0; off >>= 1) {
        a0 += __shfl_xor(a0, off);
        a1 += __shfl_xor(a1, off);
    }
    if (lane == 0) {
        out[b * 2]     = a0 + b2[0];
        out[b * 2 + 1] = a1 + b2[1];
    }
}

// emb output gather: out[b][s][:] = embedding[msg[b][s]][:]
__global__ __launch_bounds__(256) void gather_k(
    const float* __restrict__ emb, const int* __restrict__ msgs,
    float* __restrict__ out)
{
    const float4* e4 = (const float4*)emb;
    float4* o4 = (float4*)out;
    int id = blockIdx.x * 256 + threadIdx.x;
    #pragma unroll
    for (int it = 0; it < 4; ++it) {
        int p = id + it * 1048576;
        int bs = p >> 6, e = p & 63;
        int v = msgs[bs];
        o4[p] = e4[v * 64 + e];
    }
}

extern "C" void kernel_launch(void* const* d_in, const int* in_sizes, int n_in,
                              void* d_out, int out_size, void* d_ws, size_t ws_size,
                              hipStream_t stream)
{
    const float* imgr  = (const float*)d_in[0];
    const int*   msgs  = (const int*)d_in[1];
    const float* emb   = (const float*)d_in[2];
    const float* w_ih  = (const float*)d_in[3];
    const float* w_hh  = (const float*)d_in[4];
    const float* b_ih  = (const float*)d_in[5];
    const float* b_hh  = (const float*)d_in[6];
    const float* procw = (const float*)d_in[7];
    const float* procb = (const float*)d_in[8];
    const float* w1    = (const float*)d_in[9];
    const float* b1    = (const float*)d_in[10];
    const float* w2    = (const float*)d_in[11];
    const float* b2    = (const float*)d_in[12];
    float* outp = (float*)d_out;

    const size_t NEED = 9437184;   // ~9 MB
    // Fallback scratch: emb output region (67 MB) is written LAST by gather_k.
    char* ws = (ws_size >= NEED) ? (char*)d_ws : (char*)(outp + 2048);

    float*          table = (float*)(ws);                          // 256 KB
    unsigned short* Wp    = (unsigned short*)(ws + 262144);        // 2 MB
    unsigned short* h0    = (unsigned short*)(ws + 2359296);       // 1 MB
    unsigned short* h1b   = (unsigned short*)(ws + 3407872);       // 1 MB
    unsigned short* imgb  = (unsigned short*)(ws + 4456448);       // 1 MB
    unsigned short* w1p   = (unsigned short*)(ws + 5505024);       // 1 MB
    float*          hid   = (float*)(ws + 6553600);                // 2 MB
    unsigned*       flags = (unsigned*)(ws + 8650752);             // 4 KB

    hipMemsetAsync(flags, 0, 4096, stream);
    hipFuncSetAttribute((const void*)lstm_k,
                        hipFuncAttributeMaxDynamicSharedMemorySize, 151552);

    prep_k<<<3072, 256, 0, stream>>>(emb, w_ih, b_ih, b_hh, w_hh, w1, imgr,
                                     procw, procb, table, Wp, w1p, imgb);
    lstm_k<<<256, 512, 151552, stream>>>(table, Wp, msgs, h0, h1b, flags);
    mlp2_k<<<dim3(16, 16), 256, 0, stream>>>(h1b, imgb, w1p, b1, hid);
    pred2_k<<<256, 256, 0, stream>>>(hid, w2, b2, outp);
    gather_k<<<4096, 256, 0, stream>>>(emb, msgs, outp + 2048);
}

// Round 3
// 642.565 us; speedup vs baseline: 2.4407x; 2.0378x over previous
//
#include <hip/hip_runtime.h>

typedef __attribute__((ext_vector_type(8))) short bf16x8;
typedef __attribute__((ext_vector_type(4))) float f32x4;
typedef unsigned long long u64;

__device__ __forceinline__ unsigned short f2bf(float x) {
    union { float f; unsigned u; } c; c.f = x;
    unsigned u = c.u + 0x7fffu + ((c.u >> 16) & 1u);
    return (unsigned short)(u >> 16);
}
__device__ __forceinline__ unsigned pack2(float a, float b) {
    return (unsigned)f2bf(a) | ((unsigned)f2bf(b) << 16);
}
__device__ __forceinline__ float sigm(float x) { return 1.f / (1.f + __expf(-x)); }
__device__ __forceinline__ float tanh_(float x) { return 1.f - 2.f / (__expf(2.f * x) + 1.f); }

#define ALOAD(p)     __hip_atomic_load((p), __ATOMIC_RELAXED, __HIP_MEMORY_SCOPE_AGENT)
#define ASTORE(p, v) __hip_atomic_store((p), (v), __ATOMIC_RELAXED, __HIP_MEMORY_SCOPE_AGENT)

// ---------------------------------------------------------------------------
// prep: table[v][c] = emb[v] . w_ih[srow(c)] + b_ih + b_hh   (c = permuted col)
//       Wp[c][k] = bf16(w_hh[srow(c)][k]);  w1p = bf16(w1)
//       imgb[b][h] = bf16(img_rep[b] . proc_w[h] + proc_b[h])
// Permutation: c -> tile t=c>>7, c7=c&127:
//   unit U = t*32 + ((c7>>6)&1)*16 + (c7&15), gate g=(c7>>4)&3, srow = g*512+U
// ---------------------------------------------------------------------------
__global__ __launch_bounds__(256) void prep_k(
    const float* __restrict__ emb, const float* __restrict__ w_ih,
    const float* __restrict__ b_ih, const float* __restrict__ b_hh,
    const float* __restrict__ w_hh, const float* __restrict__ w1,
    const float* __restrict__ imgr, const float* __restrict__ procw,
    const float* __restrict__ procb,
    float* __restrict__ table, unsigned short* __restrict__ Wp,
    unsigned short* __restrict__ w1p, unsigned short* __restrict__ imgb)
{
    int wg = blockIdx.x, tid = threadIdx.x;
    if (wg < 256) {
        int id = wg * 256 + tid;              // v*2048 + c
        int v = id >> 11, c = id & 2047;
        int c7 = c & 127, tt = c >> 7;
        int srow = ((c7 >> 4) & 3) * 512 + tt * 32 + ((c7 >> 6) & 1) * 16 + (c7 & 15);
        const float4* e4 = (const float4*)(emb + v * 256);
        const float4* w4 = (const float4*)(w_ih + srow * 256);
        float a = 0.f;
        #pragma unroll 8
        for (int k = 0; k < 64; ++k) {
            float4 x = e4[k], y = w4[k];
            a += x.x * y.x + x.y * y.y + x.z * y.z + x.w * y.w;
        }
        table[id] = a + b_ih[srow] + b_hh[srow];
    } else if (wg < 768) {
        int id = (wg - 256) * 256 + tid;      // c*64 + j  (8 elems each)
        int c = id >> 6, j = id & 63;
        int c7 = c & 127, tt = c >> 7;
        int srow = ((c7 >> 4) & 3) * 512 + tt * 32 + ((c7 >> 6) & 1) * 16 + (c7 & 15);
        const float4* s4 = (const float4*)(w_hh + srow * 512 + j * 8);
        float4 x = s4[0], y = s4[1];
        uint4 r;
        r.x = pack2(x.x, x.y); r.y = pack2(x.z, x.w);
        r.z = pack2(y.x, y.y); r.w = pack2(y.z, y.w);
        *(uint4*)(Wp + c * 512 + j * 8) = r;
    } else if (wg < 1024) {
        int id = (wg - 768) * 256 + tid;      // 8 elems each of w1
        const float4* s4 = (const float4*)(w1 + id * 8);
        float4 x = s4[0], y = s4[1];
        uint4 r;
        r.x = pack2(x.x, x.y); r.y = pack2(x.z, x.w);
        r.z = pack2(y.x, y.y); r.w = pack2(y.z, y.w);
        *(uint4*)(w1p + id * 8) = r;
    } else {
        int id = (wg - 1024) * 256 + tid;     // b*512 + h
        int b = id >> 9, h = id & 511;
        const float* ir = imgr + b * 13;
        const float* pw = procw + h * 13;
        float a = procb[h];
        #pragma unroll
        for (int k = 0; k < 13; ++k) a += ir[k] * pw[k];
        imgb[id] = f2bf(a);
    }
}

// ---------------------------------------------------------------------------
// Persistent LSTM: 256 WGs x 512 thr, 1 WG/CU. WG x: group g=(x&7)|(((x>>7)&1)<<3)
// (rows g*64..+64), tile t=(x>>3)&15 (units t*32..+32).
// B (w_hh slice) in LDS in FRAGMENT ORDER (linear ds_read_b128, 0 conflicts).
// Cell state in registers. h double-buffered in global, ALL h traffic via
// relaxed agent-scope (sc1/IF-coherent) atomics. Per-(g,t) flag slots, plain
// relaxed stores; readers poll the 16-word line with one 16-lane load.
// No acquire-inv, no wbl2 anywhere.
// ---------------------------------------------------------------------------
__global__ __launch_bounds__(512, 2) void lstm_k(
    const float* __restrict__ table, const unsigned short* __restrict__ Wp,
    const int* __restrict__ msgs, u64* __restrict__ h0, u64* __restrict__ h1,
    unsigned* __restrict__ flags)
{
    extern __shared__ char smem[];
    uint4* BshF = (uint4*)smem;                                // 128 KB, fragment order
    float* Tsh  = (float*)(smem + 131072);                     // 16 KB table tile
    unsigned char* Msh = (unsigned char*)(smem + 147456);      // 4 KB msgs
    unsigned short* Hsh = (unsigned short*)(smem + 151552);    // [64][40] u16 = 5 KB

    const int tid = threadIdx.x;
    const int lane = tid & 63, wid = tid >> 6;
    const int wr = wid >> 1, wc = wid & 1;
    const int l15 = lane & 15, l4 = lane >> 4;
    const int x = blockIdx.x;
    const int g = (x & 7) | (((x >> 7) & 1) << 3);
    const int t = (x >> 3) & 15;

    // ---- stage B into fragment order: frag(wc,kg,cf) at [( (wc*16+kg)*4+cf )*64 + lane]
    const uint4* wg4 = (const uint4*)Wp;
    #pragma unroll
    for (int it = 0; it < 16; ++it) {
        int p = it * 512 + tid;
        int col = p >> 6, ks = p & 63;       // col: permuted gate-col in tile, ks: k/8
        uint4 v = wg4[(t * 128 + col) * 64 + ks];
        int dst = (((col >> 6) * 16 + (ks >> 2)) * 4 + ((col >> 4) & 3)) * 64
                  + (ks & 3) * 16 + (col & 15);
        BshF[dst] = v;
    }
    // ---- table tile [32 v][128 c7]
    const uint4* tg = (const uint4*)table;
    uint4* T4 = (uint4*)Tsh;
    #pragma unroll
    for (int it = 0; it < 2; ++it) {
        int p = it * 512 + tid;
        T4[p] = tg[(p >> 5) * 512 + t * 32 + (p & 31)];
    }
    // ---- msgs [s][row]
    #pragma unroll
    for (int it = 0; it < 8; ++it) {
        int p = it * 512 + tid;
        int row = p >> 6, s_ = p & 63;
        Msh[s_ * 64 + row] = (unsigned char)msgs[(g * 64 + row) * 64 + s_];
    }
    __syncthreads();

    float creg[4] = {0.f, 0.f, 0.f, 0.f};
    const int arow = g * 64 + wr * 16 + l15;   // A-fragment global row
    const int bbase = wc * 4096;               // wave's B-fragment base (uint4 units)
    unsigned* myflag = flags + g * 16;         // one 64-B line per group

    for (int s = 0; s < 64; ++s) {
        f32x4 acc[4] = {};
        if (s > 0) {
            // poll: 16 lanes cover the group's whole flag line in one load
            const unsigned tgt = (unsigned)s;
            for (;;) {
                unsigned v = ALOAD(&myflag[l15]);
                if (__all((int)(v >= tgt))) break;
                __builtin_amdgcn_s_sleep(1);
            }
            const u64* hp = (s & 1) ? h0 : h1;
            u64 a0[16], a1[16];
            #pragma unroll
            for (int kg = 0; kg < 16; ++kg) {
                int idx = arow * 128 + kg * 8 + l4 * 2;
                a0[kg] = ALOAD(&hp[idx]);
                a1[kg] = ALOAD(&hp[idx + 1]);
            }
            #pragma unroll
            for (int kg = 0; kg < 16; ++kg) {
                union { u64 u[2]; bf16x8 v; } A;
                A.u[0] = a0[kg]; A.u[1] = a1[kg];
                #pragma unroll
                for (int cf = 0; cf < 4; ++cf) {
                    bf16x8 bfr = *(const bf16x8*)&BshF[bbase + (kg * 4 + cf) * 64 + lane];
                    acc[cf] = __builtin_amdgcn_mfma_f32_16x16x32_bf16(
                        A.v, bfr, acc[cf], 0, 0, 0);
                }
            }
        }
        // fused cell update -> Hsh (LDS transpose for coalesced global store)
        #pragma unroll
        for (int reg = 0; reg < 4; ++reg) {
            int bl = wr * 16 + l4 * 4 + reg;
            int v = Msh[s * 64 + bl];
            const float* tr = Tsh + v * 128 + wc * 64 + l15;
            float gi = acc[0][reg] + tr[0];
            float gf = acc[1][reg] + tr[16];
            float gg = acc[2][reg] + tr[32];
            float go = acc[3][reg] + tr[48];
            float cn = sigm(gf) * creg[reg] + sigm(gi) * tanh_(gg);
            creg[reg] = cn;
            Hsh[bl * 40 + wc * 16 + l15] = f2bf(sigm(go) * tanh_(cn));
        }
        __syncthreads();   // Hsh complete
        {
            int row = tid >> 3, j = tid & 7;
            u64 val = *(const u64*)&Hsh[row * 40 + j * 4];
            u64* hw = (s & 1) ? h1 : h0;
            ASTORE(&hw[(g * 64 + row) * 128 + t * 8 + j], val);
        }
        __syncthreads();   // compiler drains vmcnt before s_barrier -> stores at IF
        if (tid == 0) ASTORE(&myflag[t], (unsigned)(s + 1));
    }
}

// ---------------------------------------------------------------------------
// hidden = relu([h64, img] @ w1^T + b1): M=1024,N=512,K=1024. Grid (16,16),
// tile 64x32, 4 waves split M. h read via relaxed agent loads (IF-coherent).
// ---------------------------------------------------------------------------
__global__ __launch_bounds__(256) void mlp2_k(
    const u64* __restrict__ hfin, const unsigned short* __restrict__ imgb,
    const unsigned short* __restrict__ w1p, const float* __restrict__ b1,
    float* __restrict__ hid)
{
    __shared__ uint4 ldsA[512];   // [64 rows][8 slots]
    __shared__ uint4 ldsB[256];   // [32 cols][8 slots]
    const int tid = threadIdx.x;
    const int lane = tid & 63, wid = tid >> 6;
    const int l15 = lane & 15, l4 = lane >> 4;
    const int mbase = blockIdx.y * 64;
    const int t = blockIdx.x;     // [0,16)

    const uint4* ia = (const uint4*)imgb;
    const uint4* wb = (const uint4*)w1p;   // rows of 128 uint4

    f32x4 acc[2] = {};
    uint4 ra[2], rb1;

    #pragma unroll
    for (int j = 0; j < 2; ++j) {
        int p = tid + j * 256, row = p >> 3, ss = (p & 7) ^ (row & 7);
        u64 q0 = ALOAD(&hfin[(mbase + row) * 128 + ss * 2]);
        u64 q1 = ALOAD(&hfin[(mbase + row) * 128 + ss * 2 + 1]);
        ra[j] = make_uint4((unsigned)q0, (unsigned)(q0 >> 32),
                           (unsigned)q1, (unsigned)(q1 >> 32));
    }
    {
        int col = tid >> 3, ss = (tid & 7) ^ (col & 7);
        rb1 = wb[(t * 32 + col) * 128 + ss];
    }
    #pragma unroll
    for (int j = 0; j < 2; ++j) ldsA[tid + j * 256] = ra[j];
    ldsB[tid] = rb1;
    __syncthreads();

    for (int kc = 0; kc < 16; ++kc) {
        if (kc < 15) {
            int kn = kc + 1;
            #pragma unroll
            for (int j = 0; j < 2; ++j) {
                int p = tid + j * 256, row = p >> 3, ss = (p & 7) ^ (row & 7);
                if (kn < 8) {
                    u64 q0 = ALOAD(&hfin[(mbase + row) * 128 + kn * 16 + ss * 2]);
                    u64 q1 = ALOAD(&hfin[(mbase + row) * 128 + kn * 16 + ss * 2 + 1]);
                    ra[j] = make_uint4((unsigned)q0, (unsigned)(q0 >> 32),
                                       (unsigned)q1, (unsigned)(q1 >> 32));
                } else {
                    ra[j] = ia[(mbase + row) * 64 + (kn - 8) * 8 + ss];
                }
            }
            int col = tid >> 3, ss = (tid & 7) ^ (col & 7);
            rb1 = wb[(t * 32 + col) * 128 + kn * 8 + ss];
        }
        #pragma unroll
        for (int kg = 0; kg < 2; ++kg) {
            int row = wid * 16 + l15;
            bf16x8 af = *(const bf16x8*)&ldsA[row * 8 + ((kg * 4 + l4) ^ (row & 7))];
            #pragma unroll
            for (int cf = 0; cf < 2; ++cf) {
                int col = cf * 16 + l15;
                bf16x8 bf = *(const bf16x8*)&ldsB[col * 8 + ((kg * 4 + l4) ^ (col & 7))];
                acc[cf] = __builtin_amdgcn_mfma_f32_16x16x32_bf16(af, bf, acc[cf], 0, 0, 0);
            }
        }
        if (kc < 15) {
            __syncthreads();
            #pragma unroll
            for (int j = 0; j < 2; ++j) ldsA[tid + j * 256] = ra[j];
            ldsB[tid] = rb1;
            __syncthreads();
        }
    }

    #pragma unroll
    for (int reg = 0; reg < 4; ++reg) {
        int b = mbase + wid * 16 + l4 * 4 + reg;
        #pragma unroll
        for (int cf = 0; cf < 2; ++cf) {
            int n = t * 32 + cf * 16 + l15;
            hid[b * 512 + n] = fmaxf(acc[cf][reg] + b1[n], 0.f);
        }
    }
}

// prediction: one wave per batch row, shuffle-reduce over 512 f32.
__global__ __launch_bounds__(256) void pred2_k(
    const float* __restrict__ hid, const float* __restrict__ w2,
    const float* __restrict__ b2, float* __restrict__ out)
{
    int wid = threadIdx.x >> 6, lane = threadIdx.x & 63;
    int b = blockIdx.x * 4 + wid;
    const float4* hr = (const float4*)(hid + b * 512);
    const float4* wA = (const float4*)(w2);
    const float4* wB = (const float4*)(w2 + 512);
    float a0 = 0.f, a1 = 0.f;
    #pragma unroll
    for (int j = 0; j < 2; ++j) {
        float4 h4 = hr[lane * 2 + j];
        float4 x0 = wA[lane * 2 + j], x1 = wB[lane * 2 + j];
        a0 += h4.x * x0.x + h4.y * x0.y + h4.z * x0.z + h4.w * x0.w;
        a1 += h4.x * x1.x + h4.y * x1.y + h4.z * x1.z + h4.w * x1.w;
    }
    #pragma unroll
    for (int off = 32; off > 0; off >>= 1) {
        a0 += __shfl_xor(a0, off);
        a1 += __shfl_xor(a1, off);
    }
    if (lane == 0) {
        out[b * 2]     = a0 + b2[0];
        out[b * 2 + 1] = a1 + b2[1];
    }
}

// emb output gather: out[b][s][:] = embedding[msg[b][s]][:]
__global__ __launch_bounds__(256) void gather_k(
    const float* __restrict__ emb, const int* __restrict__ msgs,
    float* __restrict__ out)
{
    const float4* e4 = (const float4*)emb;
    float4* o4 = (float4*)out;
    int id = blockIdx.x * 256 + threadIdx.x;
    #pragma unroll
    for (int it = 0; it < 4; ++it) {
        int p = id + it * 1048576;
        int bs = p >> 6, e = p & 63;
        int v = msgs[bs];
        o4[p] = e4[v * 64 + e];
    }
}

extern "C" void kernel_launch(void* const* d_in, const int* in_sizes, int n_in,
                              void* d_out, int out_size, void* d_ws, size_t ws_size,
                              hipStream_t stream)
{
    const float* imgr  = (const float*)d_in[0];
    const int*   msgs  = (const int*)d_in[1];
    const float* emb   = (const float*)d_in[2];
    const float* w_ih  = (const float*)d_in[3];
    const float* w_hh  = (const float*)d_in[4];
    const float* b_ih  = (const float*)d_in[5];
    const float* b_hh  = (const float*)d_in[6];
    const float* procw = (const float*)d_in[7];
    const float* procb = (const float*)d_in[8];
    const float* w1    = (const float*)d_in[9];
    const float* b1    = (const float*)d_in[10];
    const float* w2    = (const float*)d_in[11];
    const float* b2    = (const float*)d_in[12];
    float* outp = (float*)d_out;

    const size_t NEED = 9437184;   // ~9 MB
    // Fallback scratch: emb output region (67 MB) is written LAST by gather_k.
    char* ws = (ws_size >= NEED) ? (char*)d_ws : (char*)(outp + 2048);

    float*          table = (float*)(ws);                          // 256 KB
    unsigned short* Wp    = (unsigned short*)(ws + 262144);        // 2 MB
    u64*            h0    = (u64*)(ws + 2359296);                  // 1 MB
    u64*            h1b   = (u64*)(ws + 3407872);                  // 1 MB
    unsigned short* imgb  = (unsigned short*)(ws + 4456448);       // 1 MB
    unsigned short* w1p   = (unsigned short*)(ws + 5505024);       // 1 MB
    float*          hid   = (float*)(ws + 6553600);                // 2 MB
    unsigned*       flags = (unsigned*)(ws + 8650752);             // 1 KB (16 lines)

    hipMemsetAsync(flags, 0, 1024, stream);
    hipFuncSetAttribute((const void*)lstm_k,
                        hipFuncAttributeMaxDynamicSharedMemorySize, 156672);

    prep_k<<<3072, 256, 0, stream>>>(emb, w_ih, b_ih, b_hh, w_hh, w1, imgr,
                                     procw, procb, table, Wp, w1p, imgb);
    lstm_k<<<256, 512, 156672, stream>>>(table, Wp, msgs, h0, h1b, flags);
    mlp2_k<<<dim3(16, 16), 256, 0, stream>>>(h1b, imgb, w1p, b1, hid);
    pred2_k<<<256, 256, 0, stream>>>(hid, w2, b2, outp);
    gather_k<<<4096, 256, 0, stream>>>(emb, msgs, outp + 2048);
}